// Round 3
// baseline (985.145 us; speedup 1.0000x reference)
//
#include <hip/hip_runtime.h>

#define CH 64
#define NGRP 8
#define CPG 8              // channels per group
#define HW 65536           // 256*256
#define NBATCH 16
#define GROUP_ELEMS (CPG * HW)   // 524288
#define GN_EPS 1e-5f

// ---------------- Kernel A: per-(batch,group) sum / sumsq ----------------
// 128 (batch,group) pairs, each 524288 contiguous floats. 8 blocks per group.
__global__ __launch_bounds__(256) void gn_stats(const float* __restrict__ x,
                                                float* __restrict__ ws) {
    const int blk   = blockIdx.x;      // 0..1023
    const int grp   = blk >> 3;        // 0..127  (= b*8 + g)
    const int split = blk & 7;
    const int tid   = threadIdx.x;

    const float4* x4 = reinterpret_cast<const float4*>(x)
                     + (size_t)grp * (GROUP_ELEMS / 4)
                     + (size_t)split * (GROUP_ELEMS / 4 / 8);

    float s = 0.f, ss = 0.f;
    #pragma unroll
    for (int i = 0; i < 64; ++i) {
        float4 v = x4[i * 256 + tid];
        s  += v.x + v.y + v.z + v.w;
        ss += v.x * v.x + v.y * v.y + v.z * v.z + v.w * v.w;
    }
    // wave64 shuffle reduction
    #pragma unroll
    for (int o = 32; o > 0; o >>= 1) {
        s  += __shfl_down(s, o, 64);
        ss += __shfl_down(ss, o, 64);
    }
    if ((tid & 63) == 0) {
        atomicAdd(&ws[grp * 2 + 0], s);
        atomicAdd(&ws[grp * 2 + 1], ss);
    }
}

// ---------------- Kernel B: fused GN-apply + FFN + residual ----------------
// One thread = one pixel (all 64 channels in registers).
// out[o] = xn[o] + b2[o] + sum_c w2[o][c] * relu(b1[c] + sum_k w1[c][k]*xn[k])
__global__ __launch_bounds__(256) void fused_gn_ffn(
        const float* __restrict__ x,
        const float* __restrict__ gamma, const float* __restrict__ beta,
        const float* __restrict__ w1, const float* __restrict__ b1,
        const float* __restrict__ w2, const float* __restrict__ b2,
        const float* __restrict__ ws,
        float* __restrict__ out) {
    const int b = blockIdx.x >> 8;                         // batch
    const int p = ((blockIdx.x & 255) << 8) + threadIdx.x; // pixel in image

    const float inv_n = 1.f / (float)GROUP_ELEMS;
    float mean[NGRP], rstd[NGRP];
    #pragma unroll
    for (int g = 0; g < NGRP; ++g) {
        float s  = ws[(b * NGRP + g) * 2 + 0];
        float sq = ws[(b * NGRP + g) * 2 + 1];
        float m  = s * inv_n;
        float v  = sq * inv_n - m * m;
        mean[g] = m;
        rstd[g] = rsqrtf(v + GN_EPS);
    }

    const size_t base = (size_t)b * CH * HW + (size_t)p;

    // load + normalize all 64 channels of this pixel
    float xn[CH];
    #pragma unroll
    for (int c = 0; c < CH; ++c) {
        float v = x[base + (size_t)c * HW];
        const int g = c >> 3;                  // compile-time under unroll
        xn[c] = (v - mean[g]) * rstd[g] * gamma[c] + beta[c];
    }

    // conv1 + relu  (weights wave-uniform -> scalar loads, v_fmac v,s,v)
    float h[CH];
    #pragma unroll
    for (int o = 0; o < CH; ++o) {
        float acc = b1[o];
        #pragma unroll
        for (int c = 0; c < CH; ++c)
            acc = fmaf(w1[o * CH + c], xn[c], acc);
        h[o] = fmaxf(acc, 0.f);
    }

    // conv2 + bias + residual, nontemporal store (keep x L3-resident)
    #pragma unroll
    for (int o = 0; o < CH; ++o) {
        float acc = b2[o] + xn[o];
        #pragma unroll
        for (int c = 0; c < CH; ++c)
            acc = fmaf(w2[o * CH + c], h[c], acc);
        __builtin_nontemporal_store(acc, &out[base + (size_t)o * HW]);
    }
}

extern "C" void kernel_launch(void* const* d_in, const int* in_sizes, int n_in,
                              void* d_out, int out_size, void* d_ws, size_t ws_size,
                              hipStream_t stream) {
    const float* x     = (const float*)d_in[0];
    const float* gamma = (const float*)d_in[1];
    const float* beta  = (const float*)d_in[2];
    const float* w1    = (const float*)d_in[3];
    const float* b1    = (const float*)d_in[4];
    const float* w2    = (const float*)d_in[5];
    const float* b2    = (const float*)d_in[6];
    float* out = (float*)d_out;
    float* ws  = (float*)d_ws;

    // zero the 128*2 float accumulators (d_ws is poisoned 0xAA each run)
    hipMemsetAsync(ws, 0, NBATCH * NGRP * 2 * sizeof(float), stream);

    gn_stats<<<NBATCH * NGRP * 8, 256, 0, stream>>>(x, ws);

    const int blocks = NBATCH * (HW / 256);   // 4096
    fused_gn_ffn<<<blocks, 256, 0, stream>>>(x, gamma, beta, w1, b1, w2, b2, ws, out);
}

// Round 5
// 539.768 us; speedup vs baseline: 1.8251x; 1.8251x over previous
//
#include <hip/hip_runtime.h>

#define CH 64
#define HW 65536
#define NBATCH 16
#define GROUP_ELEMS (8 * HW)
#define GN_EPS 1e-5f

typedef __attribute__((ext_vector_type(8))) short bf16x8;
typedef __attribute__((ext_vector_type(4))) float f32x4;

// ws float-offset layout
#define WS_SUMS   0       // 128*2 floats
#define WS_FRAGS  1024    // 32 frags * 64 lanes * 4 dwords (uint)
#define WS_SCALE  16384   // 16*64 floats
#define WS_SHIFT  17408   // 16*64 floats

static __device__ __forceinline__ unsigned short f2bf(float f) {
    unsigned u = __float_as_uint(f);
    return (unsigned short)((u + 0x7fffu + ((u >> 16) & 1u)) >> 16);  // RNE
}
static __device__ __forceinline__ float bf2f(unsigned h) {
    return __uint_as_float(h << 16);
}
// XOR-swizzle: spread 128B rows across banks (bits 7..9 = pix&7 -> bits 4..6)
#define SWZ(a) ((a) ^ ((((a) >> 7) & 7) << 4))

// ---------------- Kernel A: per-(batch,group) sum / sumsq ----------------
__global__ __launch_bounds__(256, 8) void gn_stats(const float* __restrict__ x,
                                                   float* __restrict__ ws) {
    const int blk = blockIdx.x, grp = blk >> 4, split = blk & 15, tid = threadIdx.x;
    const float4* x4 = (const float4*)x + (size_t)grp * (GROUP_ELEMS / 4)
                                        + (size_t)split * (GROUP_ELEMS / 64);
    float s = 0.f, ss = 0.f;
    #pragma unroll
    for (int i = 0; i < 32; ++i) {
        float4 v = x4[i * 256 + tid];
        s  += v.x + v.y + v.z + v.w;
        ss += v.x * v.x + v.y * v.y + v.z * v.z + v.w * v.w;
    }
    #pragma unroll
    for (int o = 32; o > 0; o >>= 1) {
        s += __shfl_down(s, o, 64);
        ss += __shfl_down(ss, o, 64);
    }
    if ((tid & 63) == 0) {
        atomicAdd(&ws[grp * 2 + 0], s);
        atomicAdd(&ws[grp * 2 + 1], ss);
    }
}

// ---------------- Kernel B: weight-fragment split + GN scale/shift ----------------
// blocks 0..15: A-fragments of W1/W2 as bf16 hi/lo, MFMA 16x16x32 layout:
//   frag(mt,kt): lane l holds rows mt*16+(l&15), k = kt*32 + (l>>4)*8 + j (contiguous 8)
// block 16: scale[b][c] = rstd*gamma, shift[b][c] = beta - mean*scale
__global__ __launch_bounds__(64) void gn_setup(const float* __restrict__ w1,
                                               const float* __restrict__ w2,
                                               const float* __restrict__ gamma,
                                               const float* __restrict__ beta,
                                               float* __restrict__ ws) {
    const int bid = blockIdx.x, l = threadIdx.x;
    if (bid < 16) {
        const int mat = bid >> 3, mt = (bid >> 1) & 3, kt = bid & 1;
        const float* w = mat ? w2 : w1;
        const int row = mt * 16 + (l & 15);
        const float* p = w + row * 64 + kt * 32 + (l >> 4) * 8;
        unsigned hi[4], lo[4];
        #pragma unroll
        for (int j = 0; j < 4; ++j) {
            float v0 = p[2 * j], v1 = p[2 * j + 1];
            unsigned h0 = f2bf(v0), h1 = f2bf(v1);
            unsigned l0 = f2bf(v0 - bf2f(h0)), l1 = f2bf(v1 - bf2f(h1));
            hi[j] = h0 | (h1 << 16);
            lo[j] = l0 | (l1 << 16);
        }
        unsigned* fr = (unsigned*)ws + WS_FRAGS;
        const int fhi = (mat * 2 + 0) * 8 + mt * 2 + kt;
        const int flo = (mat * 2 + 1) * 8 + mt * 2 + kt;
        *(uint4*)(fr + fhi * 256 + l * 4) = make_uint4(hi[0], hi[1], hi[2], hi[3]);
        *(uint4*)(fr + flo * 256 + l * 4) = make_uint4(lo[0], lo[1], lo[2], lo[3]);
    } else {
        const int c = l, g = c >> 3;
        const float ga = gamma[c], be = beta[c], invn = 1.f / (float)GROUP_ELEMS;
        for (int b = 0; b < NBATCH; ++b) {
            float s  = ws[(b * 8 + g) * 2 + 0];
            float ss = ws[(b * 8 + g) * 2 + 1];
            float m  = s * invn;
            float var = ss * invn - m * m;
            float rs = rsqrtf(var + GN_EPS);
            float A = rs * ga;
            ws[WS_SCALE + b * 64 + c] = A;
            ws[WS_SHIFT + b * 64 + c] = be - m * A;
        }
    }
}

// ---------------- Kernel C: fused GN-apply + FFN (MFMA) + residual ----------------
// Block: 256 thr = 4 independent waves. Wave: 32 pixels x 64 ch.
// Per wave: stage xn (bf16 hi/lo, swizzled LDS) -> GEMM1(W1) -> relu -> H to LDS
//           -> GEMM2(W2) + residual -> store.  No __syncthreads needed.
__global__ __launch_bounds__(256, 2) void fused_gn_ffn(
        const float* __restrict__ x,
        const float* __restrict__ b1g, const float* __restrict__ b2g,
        const float* __restrict__ ws, float* __restrict__ out) {

    __shared__ __align__(16) char lds[65536];
    const int tid = threadIdx.x, wid = tid >> 6, l = tid & 63;
    const int b = blockIdx.x >> 9;
    const int pw = (blockIdx.x & 511) * 128 + wid * 32;   // wave's 32-pixel base

    char* X_hi = lds + wid * 16384;
    char* X_lo = X_hi + 4096;
    char* H_hi = X_hi + 8192;
    char* H_lo = X_hi + 12288;

    // weight fragments (pre-split bf16, L2-resident)
    const unsigned* fr = (const unsigned*)ws + WS_FRAGS;
    bf16x8 w1h[4][2], w1l[4][2], w2h[4][2], w2l[4][2];
    #pragma unroll
    for (int mt = 0; mt < 4; ++mt)
        #pragma unroll
        for (int kt = 0; kt < 2; ++kt) {
            w1h[mt][kt] = __builtin_bit_cast(bf16x8, *(const uint4*)(fr + (0  + mt * 2 + kt) * 256 + l * 4));
            w1l[mt][kt] = __builtin_bit_cast(bf16x8, *(const uint4*)(fr + (8  + mt * 2 + kt) * 256 + l * 4));
            w2h[mt][kt] = __builtin_bit_cast(bf16x8, *(const uint4*)(fr + (16 + mt * 2 + kt) * 256 + l * 4));
            w2l[mt][kt] = __builtin_bit_cast(bf16x8, *(const uint4*)(fr + (24 + mt * 2 + kt) * 256 + l * 4));
        }

    // biases in C/D layout: rows mt*16 + (l>>4)*4 .. +4
    f32x4 b1v[4], b2v[4];
    #pragma unroll
    for (int mt = 0; mt < 4; ++mt) {
        const int r = mt * 16 + (l >> 4) * 4;
        b1v[mt] = *(const f32x4*)(b1g + r);
        b2v[mt] = *(const f32x4*)(b2g + r);
    }

    // ---- stage: load x, normalize, split hi/lo, write LDS [pix][ch] swizzled ----
    const float* scale = ws + WS_SCALE + b * 64;
    const float* shift = ws + WS_SHIFT + b * 64;
    const int pixl = l & 31;
    #pragma unroll
    for (int a = 0; a < 4; ++a) {
        const int oct = (l >> 5) + 2 * a;         // 8-channel group (== GN group)
        float sc[8], sh[8];
        *(f32x4*)(sc)     = *(const f32x4*)(scale + oct * 8);
        *(f32x4*)(sc + 4) = *(const f32x4*)(scale + oct * 8 + 4);
        *(f32x4*)(sh)     = *(const f32x4*)(shift + oct * 8);
        *(f32x4*)(sh + 4) = *(const f32x4*)(shift + oct * 8 + 4);
        const float* gp = x + ((size_t)(b * 64 + oct * 8)) * HW + pw + pixl;
        float xn[8];
        #pragma unroll
        for (int j = 0; j < 8; ++j)
            xn[j] = fmaf(gp[(size_t)j * HW], sc[j], sh[j]);
        unsigned hiw[4], low[4];
        #pragma unroll
        for (int j = 0; j < 4; ++j) {
            unsigned h0 = f2bf(xn[2 * j]), h1 = f2bf(xn[2 * j + 1]);
            unsigned l0 = f2bf(xn[2 * j] - bf2f(h0));
            unsigned l1 = f2bf(xn[2 * j + 1] - bf2f(h1));
            hiw[j] = h0 | (h1 << 16);
            low[j] = l0 | (l1 << 16);
        }
        const unsigned ad = (unsigned)(pixl * 128 + oct * 16);
        *(uint4*)(X_hi + SWZ(ad)) = make_uint4(hiw[0], hiw[1], hiw[2], hiw[3]);
        *(uint4*)(X_lo + SWZ(ad)) = make_uint4(low[0], low[1], low[2], low[3]);
    }

    // ---- GEMM phase: 2 column-tiles of 16 pixels ----
    #pragma unroll
    for (int pc = 0; pc < 2; ++pc) {
        const unsigned ba = (unsigned)((pc * 16 + (l & 15)) * 128 + (l >> 4) * 16);
        bf16x8 xh0 = __builtin_bit_cast(bf16x8, *(const uint4*)(X_hi + SWZ(ba)));
        bf16x8 xh1 = __builtin_bit_cast(bf16x8, *(const uint4*)(X_hi + SWZ(ba + 64)));
        bf16x8 xl0 = __builtin_bit_cast(bf16x8, *(const uint4*)(X_lo + SWZ(ba)));
        bf16x8 xl1 = __builtin_bit_cast(bf16x8, *(const uint4*)(X_lo + SWZ(ba + 64)));

        f32x4 acc[4];
        #pragma unroll
        for (int mt = 0; mt < 4; ++mt) acc[mt] = b1v[mt];
        #pragma unroll
        for (int mt = 0; mt < 4; ++mt) {
            acc[mt] = __builtin_amdgcn_mfma_f32_16x16x32_bf16(w1h[mt][0], xh0, acc[mt], 0, 0, 0);
            acc[mt] = __builtin_amdgcn_mfma_f32_16x16x32_bf16(w1h[mt][1], xh1, acc[mt], 0, 0, 0);
            acc[mt] = __builtin_amdgcn_mfma_f32_16x16x32_bf16(w1h[mt][0], xl0, acc[mt], 0, 0, 0);
            acc[mt] = __builtin_amdgcn_mfma_f32_16x16x32_bf16(w1h[mt][1], xl1, acc[mt], 0, 0, 0);
            acc[mt] = __builtin_amdgcn_mfma_f32_16x16x32_bf16(w1l[mt][0], xh0, acc[mt], 0, 0, 0);
            acc[mt] = __builtin_amdgcn_mfma_f32_16x16x32_bf16(w1l[mt][1], xh1, acc[mt], 0, 0, 0);
        }

        // relu, split, write H (rows mt*16+(l>>4)*4.. of pixel l&15)
        #pragma unroll
        for (int mt = 0; mt < 4; ++mt) {
            float h0 = fmaxf(acc[mt][0], 0.f), h1 = fmaxf(acc[mt][1], 0.f);
            float h2 = fmaxf(acc[mt][2], 0.f), h3 = fmaxf(acc[mt][3], 0.f);
            unsigned a0 = f2bf(h0), a1 = f2bf(h1), a2 = f2bf(h2), a3 = f2bf(h3);
            unsigned c0 = f2bf(h0 - bf2f(a0)), c1 = f2bf(h1 - bf2f(a1));
            unsigned c2 = f2bf(h2 - bf2f(a2)), c3 = f2bf(h3 - bf2f(a3));
            const unsigned ha = (unsigned)((pc * 16 + (l & 15)) * 128 + mt * 32 + (l >> 4) * 8);
            *(uint2*)(H_hi + SWZ(ha)) = make_uint2(a0 | (a1 << 16), a2 | (a3 << 16));
            *(uint2*)(H_lo + SWZ(ha)) = make_uint2(c0 | (c1 << 16), c2 | (c3 << 16));
        }

        // residual + b2 as C-input
        f32x4 acc2[4];
        #pragma unroll
        for (int mt = 0; mt < 4; ++mt) {
            const unsigned ra = (unsigned)((pc * 16 + (l & 15)) * 128 + mt * 32 + (l >> 4) * 8);
            uint2 rh = *(const uint2*)(X_hi + SWZ(ra));
            uint2 rl = *(const uint2*)(X_lo + SWZ(ra));
            f32x4 res;
            res[0] = bf2f(rh.x & 0xffffu) + bf2f(rl.x & 0xffffu);
            res[1] = bf2f(rh.x >> 16)     + bf2f(rl.x >> 16);
            res[2] = bf2f(rh.y & 0xffffu) + bf2f(rl.y & 0xffffu);
            res[3] = bf2f(rh.y >> 16)     + bf2f(rl.y >> 16);
            acc2[mt] = b2v[mt] + res;
        }

        bf16x8 hh0 = __builtin_bit_cast(bf16x8, *(const uint4*)(H_hi + SWZ(ba)));
        bf16x8 hh1 = __builtin_bit_cast(bf16x8, *(const uint4*)(H_hi + SWZ(ba + 64)));
        bf16x8 hl0 = __builtin_bit_cast(bf16x8, *(const uint4*)(H_lo + SWZ(ba)));
        bf16x8 hl1 = __builtin_bit_cast(bf16x8, *(const uint4*)(H_lo + SWZ(ba + 64)));
        #pragma unroll
        for (int mt = 0; mt < 4; ++mt) {
            acc2[mt] = __builtin_amdgcn_mfma_f32_16x16x32_bf16(w2h[mt][0], hh0, acc2[mt], 0, 0, 0);
            acc2[mt] = __builtin_amdgcn_mfma_f32_16x16x32_bf16(w2h[mt][1], hh1, acc2[mt], 0, 0, 0);
            acc2[mt] = __builtin_amdgcn_mfma_f32_16x16x32_bf16(w2h[mt][0], hl0, acc2[mt], 0, 0, 0);
            acc2[mt] = __builtin_amdgcn_mfma_f32_16x16x32_bf16(w2h[mt][1], hl1, acc2[mt], 0, 0, 0);
            acc2[mt] = __builtin_amdgcn_mfma_f32_16x16x32_bf16(w2l[mt][0], hh0, acc2[mt], 0, 0, 0);
            acc2[mt] = __builtin_amdgcn_mfma_f32_16x16x32_bf16(w2l[mt][1], hh1, acc2[mt], 0, 0, 0);
        }

        // store: row = mt*16 + (l>>4)*4 + r, pixel = pw + pc*16 + (l&15)
        #pragma unroll
        for (int mt = 0; mt < 4; ++mt) {
            const int row = mt * 16 + (l >> 4) * 4;
            float* op = out + ((size_t)(b * 64 + row)) * HW + pw + pc * 16 + (l & 15);
            __builtin_nontemporal_store(acc2[mt][0], op);
            __builtin_nontemporal_store(acc2[mt][1], op + HW);
            __builtin_nontemporal_store(acc2[mt][2], op + 2 * HW);
            __builtin_nontemporal_store(acc2[mt][3], op + 3 * HW);
        }
    }
}

extern "C" void kernel_launch(void* const* d_in, const int* in_sizes, int n_in,
                              void* d_out, int out_size, void* d_ws, size_t ws_size,
                              hipStream_t stream) {
    const float* x     = (const float*)d_in[0];
    const float* gamma = (const float*)d_in[1];
    const float* beta  = (const float*)d_in[2];
    const float* w1    = (const float*)d_in[3];
    const float* b1    = (const float*)d_in[4];
    const float* w2    = (const float*)d_in[5];
    const float* b2    = (const float*)d_in[6];
    float* out = (float*)d_out;
    float* ws  = (float*)d_ws;

    hipMemsetAsync(ws, 0, 256 * sizeof(float), stream);
    gn_stats<<<2048, 256, 0, stream>>>(x, ws);
    gn_setup<<<17, 64, 0, stream>>>(w1, w2, gamma, beta, ws);
    fused_gn_ffn<<<NBATCH * 512, 256, 0, stream>>>(x, b1, b2, ws, out);
}